// Round 8
// baseline (160.896 us; speedup 1.0000x reference)
//
#include <hip/hip_runtime.h>

typedef __attribute__((ext_vector_type(8))) short bf16x8;
typedef __attribute__((ext_vector_type(16))) float f32x16;
typedef unsigned short ushort_t;

#define N 4096

__device__ __forceinline__ unsigned short f2bf_rne(float f) {
  unsigned int u = __float_as_uint(f);
  u += 0x7fffu + ((u >> 16) & 1u);
  return (unsigned short)(u >> 16);
}

// One block per row (8192 rows: Z then Y). fp32 row norm + bf16 copy.
__global__ __launch_bounds__(256) void prep_kernel(
    const float* __restrict__ Z, const float* __restrict__ Y,
    ushort_t* __restrict__ Zb, ushort_t* __restrict__ Yb,
    float* __restrict__ norms) {
  const int r = blockIdx.x;
  const bool isZ = (r < N);
  const int rr = isZ ? r : r - N;
  const float* __restrict__ src = (isZ ? Z : Y) + (size_t)rr * N;
  ushort_t* __restrict__ dst = (isZ ? Zb : Yb) + (size_t)rr * N;
  const int t = threadIdx.x;

  float s = 0.f;
#pragma unroll
  for (int j = 0; j < 4; ++j) {
    const float4 v = ((const float4*)src)[j * 256 + t];
    s += v.x * v.x + v.y * v.y + v.z * v.z + v.w * v.w;
    short4 o;
    o.x = (short)f2bf_rne(v.x);
    o.y = (short)f2bf_rne(v.y);
    o.z = (short)f2bf_rne(v.z);
    o.w = (short)f2bf_rne(v.w);
    ((short4*)dst)[j * 256 + t] = o;
  }
#pragma unroll
  for (int off = 32; off > 0; off >>= 1) s += __shfl_down(s, off, 64);
  __shared__ float red[4];
  const int lane = t & 63, w = t >> 6;
  if (lane == 0) red[w] = s;
  __syncthreads();
  if (t == 0) norms[r] = sqrtf(red[0] + red[1] + red[2] + red[3]);
}

// ---- 256x256 tile, BK=64, 8 waves (2M x 4N), 2-deep dbuf, 8-phase -------
// MFMA shape: 32x32x16 (measured 2495 TF = 99.8% dense peak vs 16x16's 2176).
// LDS per buf (64KB): A0 @0, A1 @16384, B0 @32768, B1 @49152; buf1 = +65536.
// Row = 128B, 8 slots of 16B, swizzle slot ^= (row & 7) (involution).
// Stage schedule identical to round 5 (>=2-phase gate slack, vmcnt(4) gates).
__global__ __launch_bounds__(512, 2) void gemm_kernel(
    const ushort_t* __restrict__ A,   // Zb [N][N]
    const ushort_t* __restrict__ B,   // Yb [N][N]
    const float* __restrict__ norms,  // [2N]: nx then ny
    float* __restrict__ out) {
  __shared__ __align__(16) char smem[131072];

  const int bid = blockIdx.x;                 // 256 blocks; bijective
  const int swz = (bid & 7) * 32 + (bid >> 3);
  const int tile_row = swz >> 4;
  const int tile_col = swz & 15;

  const int tid = threadIdx.x;
  const int l = tid & 63;
  const int w = tid >> 6;
  const int wr = w >> 2;      // M half (128 rows)
  const int wc = w & 3;       // N quarter (64 cols)
  const int l31 = l & 31;
  const int kh = l >> 5;      // k-half within fragment

  // staging: chunk ch = q*512 + tid writes LDS [half_base + ch*16, +16)
  // linearly; LDS(row,slot) holds global(row, slot ^ (row&7)).
  const ushort_t* pgA[2];
  const ushort_t* pgB[2];
#pragma unroll
  for (int q = 0; q < 2; ++q) {
    const int ch = q * 512 + tid;
    const int row = ch >> 3;
    const int scol = ((ch & 7) ^ (row & 7)) * 8;
    pgA[q] = A + (size_t)(tile_row * 256 + row) * N + scol;
    pgB[q] = B + (size_t)(tile_col * 256 + row) * N + scol;
  }

#define GLD(SRC, DST)                                              \
  __builtin_amdgcn_global_load_lds(                                \
      (__attribute__((address_space(1))) void*)(SRC),              \
      (__attribute__((address_space(3))) void*)(DST), 16, 0, 0)
#define STG_A(H, KK, DSTB) {                                            \
    GLD(pgA[0] + (size_t)(H)*128*N + (KK), smem + (DSTB) + w*1024);     \
    GLD(pgA[1] + (size_t)(H)*128*N + (KK), smem + (DSTB) + 8192 + w*1024); }
#define STG_B(H, KK, DSTB) {                                            \
    GLD(pgB[0] + (size_t)(H)*128*N + (KK), smem + (DSTB) + w*1024);     \
    GLD(pgB[1] + (size_t)(H)*128*N + (KK), smem + (DSTB) + 8192 + w*1024); }

  // ---- fragment addressing (32x32x16) -----------------------------------
  // A-frag (mf, ks): row = mf*32 + l31 within the wave's 128-row half
  //   (region A_wr), k = ks*16 + kh*8 -> slot = ks*2+kh, swizzled ^ (l&7).
  // B-frag (nf, ks): row = wc*64 + nf*32 + l31 in [0,256) -> region B_(wc>>1).
  const int baseA = wr * 16384 + l31 * 128;
  const int baseB = 32768 + (wc >> 1) * 16384 + ((wc & 1) * 64 + l31) * 128;
  int sx[4];
#pragma unroll
  for (int ks = 0; ks < 4; ++ks) sx[ks] = (((ks << 1) + kh) ^ (l & 7)) << 4;

  bf16x8 aR[2][4], bR0[4], bR1[4];
  f32x16 acc[4][2];
#pragma unroll
  for (int mf = 0; mf < 4; ++mf)
#pragma unroll
    for (int nf = 0; nf < 2; ++nf)
#pragma unroll
      for (int r = 0; r < 16; ++r) acc[mf][nf][r] = 0.f;

#define RDA2(BUFB, MH) { _Pragma("unroll")                                    \
    for (int mm = 0; mm < 2; ++mm)                                            \
    _Pragma("unroll") for (int ks = 0; ks < 4; ++ks)                          \
      aR[mm][ks] = *(const bf16x8*)(smem + (BUFB) + baseA +                   \
                                    ((MH)*2 + mm) * 4096 + sx[ks]); }
#define RDB(DST, BUFB, NF) { _Pragma("unroll")                                \
    for (int ks = 0; ks < 4; ++ks)                                            \
      DST[ks] = *(const bf16x8*)(smem + (BUFB) + baseB + (NF) * 4096 + sx[ks]); }

  // phase MFMA: quadrant (MH, NF): 8 x mfma_32x32x16 (2 mf x 4 ks)
#define MFQ(MH, NF, BR) {                                                     \
    __builtin_amdgcn_s_setprio(1);                                            \
    _Pragma("unroll") for (int ks = 0; ks < 4; ++ks)                          \
    _Pragma("unroll") for (int mm = 0; mm < 2; ++mm)                          \
      acc[(MH)*2+mm][NF] = __builtin_amdgcn_mfma_f32_32x32x16_bf16(           \
          aR[mm][ks], BR[ks], acc[(MH)*2+mm][NF], 0, 0, 0);                   \
    __builtin_amdgcn_s_setprio(0); }

#define BARM __builtin_amdgcn_s_barrier();
#define BARC { __builtin_amdgcn_s_barrier(); __builtin_amdgcn_sched_barrier(0); }
#define LG   { asm volatile("s_waitcnt lgkmcnt(0)" ::: "memory");             \
               __builtin_amdgcn_sched_barrier(0); }
#define VM4  asm volatile("s_waitcnt vmcnt(4)" ::: "memory");
#define VM0  asm volatile("s_waitcnt vmcnt(0)" ::: "memory");

  // ---- prologue: T0 full -> buf0; T1.B0,B1 -> buf1; gate T0 -------------
  STG_A(0, 0, 0); STG_A(1, 0, 16384);
  STG_B(0, 0, 32768); STG_B(1, 0, 49152);
  STG_B(0, 64, 98304); STG_B(1, 64, 114688);
  VM4; BARC;

  // ---- main loop: iter k computes K-tiles 2k (buf0), 2k+1 (buf1) --------
  for (int k = 0; k < 31; ++k) {
    const int kk0 = k * 128;
    // ph1
    RDA2(0, 0); RDB(bR0, 0, 0); STG_A(0, kk0 + 64, 65536);
    BARM; LG; MFQ(0, 0, bR0); BARC;
    // ph2
    RDB(bR1, 0, 1); STG_A(1, kk0 + 64, 81920);
    BARM; LG; MFQ(0, 1, bR1); BARC;
    // ph3
    RDA2(0, 1); STG_B(0, kk0 + 128, 32768);
    BARM; LG; MFQ(1, 0, bR0); BARC;
    // ph4
    STG_B(1, kk0 + 128, 49152); VM4;
    BARM; LG; MFQ(1, 1, bR1); BARC;
    // ph5
    RDA2(65536, 0); RDB(bR0, 65536, 0); STG_A(0, kk0 + 128, 0);
    BARM; LG; MFQ(0, 0, bR0); BARC;
    // ph6
    RDB(bR1, 65536, 1); STG_A(1, kk0 + 128, 16384);
    BARM; LG; MFQ(0, 1, bR1); BARC;
    // ph7
    RDA2(65536, 1); STG_B(0, kk0 + 192, 98304);
    BARM; LG; MFQ(1, 0, bR0); BARC;
    // ph8
    STG_B(1, kk0 + 192, 114688); VM4;
    BARM; LG; MFQ(1, 1, bR1); BARC;
  }

  // ---- tail: k = 31 (K-tiles 62, 63); only A63 remains to stage ---------
  {
    RDA2(0, 0); RDB(bR0, 0, 0); STG_A(0, 31 * 128 + 64, 65536);
    BARM; LG; MFQ(0, 0, bR0); BARC;
    RDB(bR1, 0, 1); STG_A(1, 31 * 128 + 64, 81920);
    BARM; LG; MFQ(0, 1, bR1); BARC;
    RDA2(0, 1);
    BARM; LG; MFQ(1, 0, bR0); BARC;
    VM0;
    BARM; LG; MFQ(1, 1, bR1); BARC;
    // K-tile 63: all resident, no more LDS writes -> no barriers needed
    RDA2(65536, 0); RDB(bR0, 65536, 0);
    LG; MFQ(0, 0, bR0);
    RDB(bR1, 65536, 1);
    LG; MFQ(0, 1, bR1);
    RDA2(65536, 1);
    LG; MFQ(1, 0, bR0);
    MFQ(1, 1, bR1);
  }

  // ---- epilogue: cosine normalize ---------------------------------------
  // 32x32 C/D layout: col = l&31, row = (reg&3) + 8*(reg>>2) + 4*(l>>5)
  const float* nx = norms;
  const float* ny = norms + N;
  const int row0 = tile_row * 256 + wr * 128 + 4 * kh;
  const int col0 = tile_col * 256 + wc * 64 + l31;
#pragma unroll
  for (int mf = 0; mf < 4; ++mf) {
#pragma unroll
    for (int rg = 0; rg < 4; ++rg) {       // reg>>2
#pragma unroll
      for (int rr = 0; rr < 4; ++rr) {     // reg&3
        const int row = row0 + mf * 32 + rg * 8 + rr;
        const float nxr = nx[row];
#pragma unroll
        for (int nf = 0; nf < 2; ++nf) {
          const int col = col0 + nf * 32;
          const float denom = fmaxf(nxr * ny[col], 1e-8f);
          out[(size_t)row * N + col] = acc[mf][nf][rg * 4 + rr] / denom;
        }
      }
    }
  }
}

extern "C" void kernel_launch(void* const* d_in, const int* in_sizes, int n_in,
                              void* d_out, int out_size, void* d_ws, size_t ws_size,
                              hipStream_t stream) {
  const float* Z = (const float*)d_in[0];
  const float* Y = (const float*)d_in[1];
  float* out = (float*)d_out;

  ushort_t* Zb = (ushort_t*)d_ws;
  ushort_t* Yb = Zb + (size_t)N * N;
  float* norms = (float*)(Yb + (size_t)N * N);

  prep_kernel<<<2 * N, 256, 0, stream>>>(Z, Y, Zb, Yb, norms);
  gemm_kernel<<<(N / 256) * (N / 256), 512, 0, stream>>>(Zb, Yb, norms, out);
}